// Round 7
// baseline (493.059 us; speedup 1.0000x reference)
//
#include <hip/hip_runtime.h>
#include <stdint.h>

// Problem shape (fixed by the reference): M = B*S = 8192, K = DIN = 4096, N = DOUT = 4096
#define MDIM 8192
#define KDIM 4096
#define NDIM 4096
#define BK   64
#define NKT  (KDIM / BK)   // 64 K-tiles

typedef float f32x4 __attribute__((ext_vector_type(4)));
typedef _Float16 h16x8 __attribute__((ext_vector_type(8)));
typedef float fl4 __attribute__((ext_vector_type(4)));
typedef int i32x4 __attribute__((ext_vector_type(4)));

// async global->LDS, 16B per lane; LDS dest is wave-uniform base + lane*16 (HW semantics)
__device__ __forceinline__ void gload_lds16(const void* g, void* l) {
    __builtin_amdgcn_global_load_lds(
        (__attribute__((address_space(1))) void*)(uintptr_t)g,
        (__attribute__((address_space(3))) void*)(uintptr_t)l,
        16, 0, 0);
}

// ---------------- fused quant: one dispatch, both tensors ----------------
// R10: unrolled x2 (16 elems/thread/iter, 4 grid-stride iters) -> 4 x 16B loads in
// flight per thread for better BW saturation (was 2).
// blocks [0,2048): x fp32 -> xq fp16 (rint(x/is); integer-valued |v|<~350: fp16-exact)
// blocks [2048,3072): w int32 -> wq fp16 (|w|<=127: exact)
__global__ void __launch_bounds__(256) quant_kernel(const float* __restrict__ x,
                                                    short* __restrict__ xq,
                                                    const int* __restrict__ w,
                                                    short* __restrict__ wq,
                                                    const float* __restrict__ p_is) {
    if (blockIdx.x < 2048) {
        const float inv_is = 1.0f / p_is[0];
        const int64_t stride = (int64_t)2048 * 256 * 16;
        for (int64_t i = ((int64_t)blockIdx.x * 256 + threadIdx.x) * 16;
             i < (int64_t)MDIM * KDIM; i += stride) {
            fl4 a = __builtin_nontemporal_load((const fl4*)(x + i));
            fl4 b = __builtin_nontemporal_load((const fl4*)(x + i + 4));
            fl4 c = __builtin_nontemporal_load((const fl4*)(x + i + 8));
            fl4 d = __builtin_nontemporal_load((const fl4*)(x + i + 12));
            h16x8 o0, o1;
            o0[0] = (_Float16)rintf(a[0] * inv_is);
            o0[1] = (_Float16)rintf(a[1] * inv_is);
            o0[2] = (_Float16)rintf(a[2] * inv_is);
            o0[3] = (_Float16)rintf(a[3] * inv_is);
            o0[4] = (_Float16)rintf(b[0] * inv_is);
            o0[5] = (_Float16)rintf(b[1] * inv_is);
            o0[6] = (_Float16)rintf(b[2] * inv_is);
            o0[7] = (_Float16)rintf(b[3] * inv_is);
            o1[0] = (_Float16)rintf(c[0] * inv_is);
            o1[1] = (_Float16)rintf(c[1] * inv_is);
            o1[2] = (_Float16)rintf(c[2] * inv_is);
            o1[3] = (_Float16)rintf(c[3] * inv_is);
            o1[4] = (_Float16)rintf(d[0] * inv_is);
            o1[5] = (_Float16)rintf(d[1] * inv_is);
            o1[6] = (_Float16)rintf(d[2] * inv_is);
            o1[7] = (_Float16)rintf(d[3] * inv_is);
            *(h16x8*)(xq + i)     = o0;   // normal store: gemm re-reads xq
            *(h16x8*)(xq + i + 8) = o1;
        }
    } else {
        const int64_t stride = (int64_t)1024 * 256 * 16;
        for (int64_t i = (((int64_t)blockIdx.x - 2048) * 256 + threadIdx.x) * 16;
             i < (int64_t)NDIM * KDIM; i += stride) {
            i32x4 a = *(const i32x4*)(w + i);
            i32x4 b = *(const i32x4*)(w + i + 4);
            i32x4 c = *(const i32x4*)(w + i + 8);
            i32x4 d = *(const i32x4*)(w + i + 12);
            h16x8 o0, o1;
            o0[0] = (_Float16)(float)a[0];
            o0[1] = (_Float16)(float)a[1];
            o0[2] = (_Float16)(float)a[2];
            o0[3] = (_Float16)(float)a[3];
            o0[4] = (_Float16)(float)b[0];
            o0[5] = (_Float16)(float)b[1];
            o0[6] = (_Float16)(float)b[2];
            o0[7] = (_Float16)(float)b[3];
            o1[0] = (_Float16)(float)c[0];
            o1[1] = (_Float16)(float)c[1];
            o1[2] = (_Float16)(float)c[2];
            o1[3] = (_Float16)(float)c[3];
            o1[4] = (_Float16)(float)d[0];
            o1[5] = (_Float16)(float)d[1];
            o1[6] = (_Float16)(float)d[2];
            o1[7] = (_Float16)(float)d[3];
            *(h16x8*)(wq + i)     = o0;
            *(h16x8*)(wq + i + 8) = o1;
        }
    }
}

// ---------------- GEMM: 256x256 tile, BK=64, 8 waves, 8-phase, relaxed drain ----------------
// R10 = R6 gemm with ONE change: PH_MID no longer force-drains lgkmcnt(0) (nor pins with
// sched_barrier). The phase's ds_reads are compiler-generated loads with proper VGPR deps,
// so SIInsertWaitcnts emits fine-grained lgkmcnt(N) per first-use -> LDS service of the
// 8 waves' reads overlaps the early MFMAs instead of serializing between the barriers.
// (Rule #18 only applies to inline-asm ds_reads; ours are not.)
// Safety: within every phase, read regions and stage regions are disjoint (A vs B or
// buf0 vs buf1), so intra-phase reordering is harmless; PH_END keeps sched_barrier(0) so
// nothing crosses phase ends and the vmcnt(6) count math is preserved (gload/asm are
// side-effecting -> program order among them fixed).
//
// Stage map (unchanged from R6; 3 half-tiles in flight, vmcnt(6) at P3/P7):
//   P0: buf1.A.h1<-t1; P2: buf0.B.h0<-tA; P3: buf0.B.h1+A.h0<-tA; P4: buf0.A.h1<-tA;
//   P6: buf1.B.h0<-tB; P7: buf1.B.h1+A.h0<-tB.
// Queue proof: P3-end 14 outstanding, oldest 8 = buf1(t1) -> vmcnt(6); P7-end 14, oldest
// 8 = buf0(tA) -> vmcnt(6). Never vmcnt(0) in loop.

#define PH_MID() do { \
    __builtin_amdgcn_s_barrier(); \
    __builtin_amdgcn_s_setprio(1); \
  } while (0)

#define PH_END() do { \
    __builtin_amdgcn_s_setprio(0); \
    __builtin_amdgcn_s_barrier(); \
    __builtin_amdgcn_sched_barrier(0); \
  } while (0)

#define PH_END_VM6() do { \
    __builtin_amdgcn_s_setprio(0); \
    asm volatile("s_waitcnt vmcnt(6)" ::: "memory"); \
    __builtin_amdgcn_s_barrier(); \
    __builtin_amdgcn_sched_barrier(0); \
  } while (0)

__global__ void __launch_bounds__(512, 2) gemm_f16_kernel(
    const short* __restrict__ A,     // [MDIM][KDIM] fp16 bits (xq)
    const short* __restrict__ Bw,    // [NDIM][KDIM] fp16 bits (wq)
    const int* __restrict__ bias,    // [NDIM]
    const float* __restrict__ wscale,// [NDIM]
    const float* __restrict__ p_is,
    const float* __restrict__ p_os,
    int* __restrict__ out) {         // [MDIM][NDIM] int32
    // A bufs: lds[b*16384 + row*64 + ch*8]; B bufs: +32768. 65536 shorts = 128 KiB.
    __shared__ __align__(16) short lds[65536];

    const int tid  = threadIdx.x;
    const int lane = tid & 63;
    const int wave = tid >> 6;
    const int quad = lane >> 4;
    const int r16  = lane & 15;
    const int sw   = r16 & 7;

    // T1: bijective XCD swizzle over the 32x16 grid
    const int flat  = blockIdx.y * gridDim.x + blockIdx.x;
    const int wgid  = (flat & 7) * 64 + (flat >> 3);
    const int m_blk = wgid >> 4;       // 0..31
    const int n_blk = wgid & 15;       // 0..15
    const int m0 = m_blk * 256;
    const int n0 = n_blk * 256;

    const int wmi = wave >> 2;         // 0..1  M wave-row (128 rows each)
    const int wni = wave & 3;          // 0..3  N wave-col (64 cols each)

    // ---- staging (write side): chunk c = l*512 + tid; row=c>>3, kc=c&7;
    //      source column chunk = kc ^ (row&7)  (rows +64 keep row&7 -> per-thread const)
    const int srow = tid >> 3;                       // 0..63
    const int skc  = (tid & 7) ^ (srow & 7);
    const short* gA = A  + (int64_t)(m0 + srow) * KDIM + skc * 8;
    const short* gB = Bw + (int64_t)(n0 + srow) * KDIM + skc * 8;

#define STAGE_A(b, ha, T) do { \
    const short* _g = gA + (int64_t)((ha) * 128) * KDIM + (T) * BK; \
    gload_lds16(_g,             &lds[(b)*16384 + (ha)*8192 + wave*512]); \
    gload_lds16(_g + 64*KDIM,   &lds[(b)*16384 + (ha)*8192 + 4096 + wave*512]); \
  } while (0)
#define STAGE_B(b, ha, T) do { \
    const short* _g = gB + (int64_t)((ha) * 128) * KDIM + (T) * BK; \
    gload_lds16(_g,             &lds[32768 + (b)*16384 + (ha)*8192 + wave*512]); \
    gload_lds16(_g + 64*KDIM,   &lds[32768 + (b)*16384 + (ha)*8192 + 4096 + wave*512]); \
  } while (0)

    // ---- read side: row = <mult of 8> + r16, so row&7 == sw; chunk = (ks*4|quad)^sw
    const int aRowOff = (wmi * 128 + r16) * 64;          // + (mh*64 + mi*16)*64
    const int bRowOff = 32768 + (wni * 64 + r16) * 64;   // + (nh*32 + nj*16)*64
    const int cOff0   = (quad ^ sw) * 8;
    const int cOff1   = cOff0 ^ 32;                      // ks=1 flips chunk bit 2

#define LDA(b, mh, mi, ks) \
    (*(const h16x8*)&lds[(b)*16384 + aRowOff + ((mh)*64 + (mi)*16)*64 + ((ks) ? cOff1 : cOff0)])
#define LDB(b, nh, nj, ks) \
    (*(const h16x8*)&lds[(b)*16384 + bRowOff + ((nh)*32 + (nj)*16)*64 + ((ks) ? cOff1 : cOff0)])

#define READ_A(b, mh) do { \
    _Pragma("unroll") for (int mi = 0; mi < 4; ++mi) { \
        aR[mi][0] = LDA(b, mh, mi, 0); aR[mi][1] = LDA(b, mh, mi, 1); } \
  } while (0)
#define READ_B(b, nh, dst) do { \
    _Pragma("unroll") for (int nj = 0; nj < 2; ++nj) { \
        dst[nj][0] = LDB(b, nh, nj, 0); dst[nj][1] = LDB(b, nh, nj, 1); } \
  } while (0)
#define MFMA_Q(mh, nh, bsrc) do { \
    _Pragma("unroll") for (int mi = 0; mi < 4; ++mi) \
    _Pragma("unroll") for (int nj = 0; nj < 2; ++nj) \
    _Pragma("unroll") for (int ks = 0; ks < 2; ++ks) \
        acc[(mh)*4 + mi][(nh)*2 + nj] = __builtin_amdgcn_mfma_f32_16x16x32_f16( \
            aR[mi][ks], bsrc[nj][ks], acc[(mh)*4 + mi][(nh)*2 + nj], 0, 0, 0); \
  } while (0)

    f32x4 acc[8][4];
#pragma unroll
    for (int i = 0; i < 8; ++i)
#pragma unroll
        for (int j = 0; j < 4; ++j) acc[i][j] = (f32x4)0.0f;

    h16x8 aR[4][2], bLo[2][2], bHi[2][2];

    // ---- prologue: t0 fully (8 ops) + t1 {B.h0, B.h1, A.h0} (6 ops); A.h1 of t1 at P0 ----
    STAGE_B(0, 0, 0);  STAGE_B(0, 1, 0);
    STAGE_A(0, 0, 0);  STAGE_A(0, 1, 0);
    STAGE_B(1, 0, 1);  STAGE_B(1, 1, 1);
    STAGE_A(1, 0, 1);
    asm volatile("s_waitcnt vmcnt(6)" ::: "memory");   // t0's 8 (oldest) landed
    __builtin_amdgcn_s_barrier();
    __builtin_amdgcn_sched_barrier(0);

    for (int it = 0; it < NKT / 2; ++it) {
        const int t1 = 2 * it + 1;
        const int tA = (2 * it + 2) & (NKT - 1);   // wraps harmlessly on last iter
        const int tB = (2 * it + 3) & (NKT - 1);

        // P0: compute buf0 q(mh0,nlo); stage buf1.A.h1<-t1
        READ_A(0, 0); READ_B(0, 0, bLo);
        STAGE_A(1, 1, t1);
        PH_MID(); MFMA_Q(0, 0, bLo); PH_END();
        // P1: q(mh0,nhi); no stage
        READ_B(0, 1, bHi);
        PH_MID(); MFMA_Q(0, 1, bHi); PH_END();
        // P2: q(mh1,nhi); stage buf0.B.h0<-tA (B regs cached since P1)
        READ_A(0, 1);
        STAGE_B(0, 0, tA);
        PH_MID(); MFMA_Q(1, 1, bHi); PH_END();
        // P3: q(mh1,nlo); stage buf0.B.h1 + buf0.A.h0 <- tA; vmcnt(6): buf1(t1) landed
        STAGE_B(0, 1, tA);
        STAGE_A(0, 0, tA);
        PH_MID(); MFMA_Q(1, 0, bLo); PH_END_VM6();
        // P4: compute buf1 q(mh0,nlo); stage buf0.A.h1<-tA
        READ_A(1, 0); READ_B(1, 0, bLo);
        STAGE_A(0, 1, tA);
        PH_MID(); MFMA_Q(0, 0, bLo); PH_END();
        // P5: q(mh0,nhi); no stage
        READ_B(1, 1, bHi);
        PH_MID(); MFMA_Q(0, 1, bHi); PH_END();
        // P6: q(mh1,nhi); stage buf1.B.h0<-tB
        READ_A(1, 1);
        STAGE_B(1, 0, tB);
        PH_MID(); MFMA_Q(1, 1, bHi); PH_END();
        // P7: q(mh1,nlo); stage buf1.B.h1 + buf1.A.h0 <- tB; vmcnt(6): buf0(tA) landed
        STAGE_B(1, 1, tB);
        STAGE_A(1, 0, tB);
        PH_MID(); MFMA_Q(1, 0, bLo); PH_END_VM6();
    }

    // ---- epilogue: out = round((is*ws[n]*acc + bias[n]) / os) ----
    const float is = p_is[0];
    const float inv_os = 1.0f / p_os[0];
    const int colBase = n0 + wni * 64;

    float alpha[4], beta[4];
#pragma unroll
    for (int nj = 0; nj < 4; ++nj) {
        const int col = colBase + nj * 16 + r16;
        alpha[nj] = is * wscale[col] * inv_os;
        beta[nj]  = (float)bias[col] * inv_os;
    }

    // C/D layout (verified m89/m91, dtype-independent): col = lane&15, row = quad*4 + reg
#pragma unroll
    for (int mi = 0; mi < 8; ++mi) {
        const int row0 = m0 + wmi * 128 + mi * 16 + quad * 4;
#pragma unroll
        for (int nj = 0; nj < 4; ++nj) {
            const int col = colBase + nj * 16 + r16;
#pragma unroll
            for (int reg = 0; reg < 4; ++reg) {
                const float v = acc[mi][nj][reg] * alpha[nj] + beta[nj];
                __builtin_nontemporal_store(__float2int_rn(v),
                                            out + (int64_t)(row0 + reg) * NDIM + col);
            }
        }
    }
}

extern "C" void kernel_launch(void* const* d_in, const int* in_sizes, int n_in,
                              void* d_out, int out_size, void* d_ws, size_t ws_size,
                              hipStream_t stream) {
    (void)in_sizes; (void)n_in; (void)out_size; (void)ws_size;
    const float* x      = (const float*)d_in[0];
    const int*   weight = (const int*)d_in[1];
    const int*   bias   = (const int*)d_in[2];
    const float* wscale = (const float*)d_in[3];
    const float* p_is   = (const float*)d_in[4];
    const float* p_os   = (const float*)d_in[5];

    // workspace: xq fp16 [M,K] (64 MiB) + wq fp16 [N,K] (32 MiB) = 96 MiB
    short* xq = (short*)d_ws;
    short* wq = xq + (size_t)MDIM * KDIM;

    quant_kernel<<<3072, 256, 0, stream>>>(x, xq, weight, wq, p_is);

    dim3 grid(NDIM / 256, MDIM / 256);   // 16 x 32 = 512 blocks
    gemm_f16_kernel<<<grid, 512, 0, stream>>>(xq, wq, bias, wscale, p_is, p_os, (int*)d_out);
}

// Round 8
// 483.608 us; speedup vs baseline: 1.0195x; 1.0195x over previous
//
#include <hip/hip_runtime.h>
#include <stdint.h>

// Problem shape (fixed by the reference): M = B*S = 8192, K = DIN = 4096, N = DOUT = 4096
#define MDIM 8192
#define KDIM 4096
#define NDIM 4096
#define BK   64
#define NKT  (KDIM / BK)   // 64 K-tiles

typedef float f32x4 __attribute__((ext_vector_type(4)));
typedef _Float16 h16x8 __attribute__((ext_vector_type(8)));
typedef float fl4 __attribute__((ext_vector_type(4)));
typedef int i32x4 __attribute__((ext_vector_type(4)));

// async global->LDS, 16B per lane; LDS dest is wave-uniform base + lane*16 (HW semantics)
__device__ __forceinline__ void gload_lds16(const void* g, void* l) {
    __builtin_amdgcn_global_load_lds(
        (__attribute__((address_space(1))) void*)(uintptr_t)g,
        (__attribute__((address_space(3))) void*)(uintptr_t)l,
        16, 0, 0);
}

// ---------------- fused quant: one dispatch, both tensors ----------------
// blocks [0,2048): x fp32 -> xq fp16 (rint(x/is); integer-valued |v|<~350: fp16-exact)
// blocks [2048,3072): w int32 -> wq fp16 (|w|<=127: exact)
__global__ void __launch_bounds__(256) quant_kernel(const float* __restrict__ x,
                                                    short* __restrict__ xq,
                                                    const int* __restrict__ w,
                                                    short* __restrict__ wq,
                                                    const float* __restrict__ p_is) {
    if (blockIdx.x < 2048) {
        const float inv_is = 1.0f / p_is[0];
        const int64_t stride = (int64_t)2048 * 256 * 8;
        for (int64_t i = ((int64_t)blockIdx.x * 256 + threadIdx.x) * 8;
             i < (int64_t)MDIM * KDIM; i += stride) {
            fl4 a = __builtin_nontemporal_load((const fl4*)(x + i));
            fl4 b = __builtin_nontemporal_load((const fl4*)(x + i + 4));
            h16x8 o;
            o[0] = (_Float16)rintf(a[0] * inv_is);
            o[1] = (_Float16)rintf(a[1] * inv_is);
            o[2] = (_Float16)rintf(a[2] * inv_is);
            o[3] = (_Float16)rintf(a[3] * inv_is);
            o[4] = (_Float16)rintf(b[0] * inv_is);
            o[5] = (_Float16)rintf(b[1] * inv_is);
            o[6] = (_Float16)rintf(b[2] * inv_is);
            o[7] = (_Float16)rintf(b[3] * inv_is);
            *(h16x8*)(xq + i) = o;   // normal store: gemm re-reads xq
        }
    } else {
        const int64_t stride = (int64_t)1024 * 256 * 8;
        for (int64_t i = (((int64_t)blockIdx.x - 2048) * 256 + threadIdx.x) * 8;
             i < (int64_t)NDIM * KDIM; i += stride) {
            i32x4 a = *(const i32x4*)(w + i);
            i32x4 b = *(const i32x4*)(w + i + 4);
            h16x8 o;
            o[0] = (_Float16)(float)a[0];
            o[1] = (_Float16)(float)a[1];
            o[2] = (_Float16)(float)a[2];
            o[3] = (_Float16)(float)a[3];
            o[4] = (_Float16)(float)b[0];
            o[5] = (_Float16)(float)b[1];
            o[6] = (_Float16)(float)b[2];
            o[7] = (_Float16)(float)b[3];
            *(h16x8*)(wq + i) = o;
        }
    }
}

// ---------- GEMM: 256x256, BK=64, 8 waves 4Mx2N, in-region LDS-read pipelining ----------
// R11 theory: in the lockstep 8-phase structure, LDS service (1750 cyc/tile) never
// overlaps MFMA (2637 cyc/tile): every phase drains its reads BEFORE its MFMA cluster,
// and the next phase's reads are issued after the cluster. Fix: issue quadrant q+1's
// ds_reads INSIDE quadrant q's MFMA region (serviced by LDS unit under the matrix pipe,
// drained ~free at the next PH_MID). Wave split 4Mx2N (per-wave 64x128) makes this fit
// the register budget: A = 8 frags (32 VGPR) cached per tile; B = 4 quadrants x 4 frags
// double-buffered in 2 groups (32 VGPR) -> frag total 64 (same as R6's 124-VGPR build).
//
// Per tile t (compute buf b = t&1; stage T2 = t+2 -> buf b, intra-buffer recycling):
//   P0-pre: READ A(8)+B0(4)           [only exposed drain, ~750 cyc]
//   P0:     MID; {READ B1 || MFMA q0}; END
//   P1-pre: STAGE A<-T2 (4 gloads)    [A reads drained P0-MID, all waves by P0-END]
//   P1:     MID; {READ B2 || MFMA q1}; END
//   P2-pre: READ B3(4)                [~200 cyc exposed]
//   P2:     MID; MFMA q2; END
//   P3-pre: STAGE B<-T2 (4 gloads)    [all B reads drained by P2-MID, waves by P2-END]
//   P3:     MID; MFMA q3; setprio0; vmcnt(8); barrier
// vmcnt(8): at P3-END outstanding = prev tile's 8 (t+1 data) + this tile's 8 (T2);
// drain the oldest 8 -> buf_o(t+1) landed with ~1.5-tile margin. NEVER vmcnt(0) in loop.
// Region safety: every region is overwritten only after its readers drained at a PH_MID
// AND a subsequent barrier (P0-END for A, P2-END for B) -- all waves provably done.
// Accumulation order per acc element identical to R2/R6 (t ascending, ks 0,1) -> same numerics.

#define PH_MID() do { \
    __builtin_amdgcn_s_barrier(); \
    asm volatile("s_waitcnt lgkmcnt(0)" ::: "memory"); \
    __builtin_amdgcn_sched_barrier(0); \
    __builtin_amdgcn_s_setprio(1); \
  } while (0)

#define PH_END() do { \
    __builtin_amdgcn_s_setprio(0); \
    __builtin_amdgcn_s_barrier(); \
    __builtin_amdgcn_sched_barrier(0); \
  } while (0)

#define PH_END_VM8() do { \
    __builtin_amdgcn_s_setprio(0); \
    asm volatile("s_waitcnt vmcnt(8)" ::: "memory"); \
    __builtin_amdgcn_s_barrier(); \
    __builtin_amdgcn_sched_barrier(0); \
  } while (0)

__global__ void __launch_bounds__(512, 2) gemm_f16_kernel(
    const short* __restrict__ A,     // [MDIM][KDIM] fp16 bits (xq)
    const short* __restrict__ Bw,    // [NDIM][KDIM] fp16 bits (wq)
    const int* __restrict__ bias,    // [NDIM]
    const float* __restrict__ wscale,// [NDIM]
    const float* __restrict__ p_is,
    const float* __restrict__ p_os,
    int* __restrict__ out) {         // [MDIM][NDIM] int32
    // A bufs: lds[b*16384 + row*64 + ch*8]; B bufs: +32768. 65536 shorts = 128 KiB.
    __shared__ __align__(16) short lds[65536];

    const int tid  = threadIdx.x;
    const int lane = tid & 63;
    const int wave = tid >> 6;
    const int quad = lane >> 4;
    const int r16  = lane & 15;
    const int sw   = r16 & 7;

    // T1: bijective XCD swizzle over the 32x16 grid
    const int flat  = blockIdx.y * gridDim.x + blockIdx.x;
    const int wgid  = (flat & 7) * 64 + (flat >> 3);
    const int m_blk = wgid >> 4;       // 0..31
    const int n_blk = wgid & 15;       // 0..15
    const int m0 = m_blk * 256;
    const int n0 = n_blk * 256;

    const int wmi = wave >> 1;         // 0..3  M wave-row (64 rows each)
    const int wni = wave & 1;          // 0..1  N wave-col (128 cols each)

    // ---- staging (write side): chunk c = l*512 + tid; row=c>>3, kc=c&7;
    //      source column chunk = kc ^ (row&7)  (rows +64 keep row&7 -> per-thread const)
    const int srow = tid >> 3;                       // 0..63
    const int skc  = (tid & 7) ^ (srow & 7);
    const short* gA = A  + (int64_t)(m0 + srow) * KDIM + skc * 8;
    const short* gB = Bw + (int64_t)(n0 + srow) * KDIM + skc * 8;

#define STAGE_A(b, ha, T) do { \
    const short* _g = gA + (int64_t)((ha) * 128) * KDIM + (T) * BK; \
    gload_lds16(_g,             &lds[(b)*16384 + (ha)*8192 + wave*512]); \
    gload_lds16(_g + 64*KDIM,   &lds[(b)*16384 + (ha)*8192 + 4096 + wave*512]); \
  } while (0)
#define STAGE_B(b, ha, T) do { \
    const short* _g = gB + (int64_t)((ha) * 128) * KDIM + (T) * BK; \
    gload_lds16(_g,             &lds[32768 + (b)*16384 + (ha)*8192 + wave*512]); \
    gload_lds16(_g + 64*KDIM,   &lds[32768 + (b)*16384 + (ha)*8192 + 4096 + wave*512]); \
  } while (0)

    // ---- read side: row = <mult of 16> + r16, so row&7 == sw; chunk = (ks*4|quad)^sw
    const int aRowOff = (wmi * 64 + r16) * 64;           // + mi*16*64
    const int bRowOff = 32768 + (wni * 128 + r16) * 64;  // + nj*16*64 (nj global 0..7)
    const int cOff0   = (quad ^ sw) * 8;
    const int cOff1   = cOff0 ^ 32;                      // ks=1 flips chunk bit 2

#define LDA(b, mi, ks) \
    (*(const h16x8*)&lds[(b)*16384 + aRowOff + (mi)*1024 + ((ks) ? cOff1 : cOff0)])
#define LDB(b, nj, ks) \
    (*(const h16x8*)&lds[(b)*16384 + bRowOff + (nj)*1024 + ((ks) ? cOff1 : cOff0)])

#define READ_A(b) do { \
    _Pragma("unroll") for (int mi = 0; mi < 4; ++mi) { \
        aR[mi][0] = LDA(b, mi, 0); aR[mi][1] = LDA(b, mi, 1); } \
  } while (0)
#define READ_BQ(b, q, dst) do { \
    _Pragma("unroll") for (int nj = 0; nj < 2; ++nj) { \
        dst[nj][0] = LDB(b, 2*(q) + nj, 0); dst[nj][1] = LDB(b, 2*(q) + nj, 1); } \
  } while (0)
#define MFMA_Q(q, bsrc) do { \
    _Pragma("unroll") for (int mi = 0; mi < 4; ++mi) \
    _Pragma("unroll") for (int nj = 0; nj < 2; ++nj) \
    _Pragma("unroll") for (int ks = 0; ks < 2; ++ks) \
        acc[mi][2*(q) + nj] = __builtin_amdgcn_mfma_f32_16x16x32_f16( \
            aR[mi][ks], bsrc[nj][ks], acc[mi][2*(q) + nj], 0, 0, 0); \
  } while (0)

    f32x4 acc[4][8];
#pragma unroll
    for (int i = 0; i < 4; ++i)
#pragma unroll
        for (int j = 0; j < 8; ++j) acc[i][j] = (f32x4)0.0f;

    h16x8 aR[4][2], bG0[2][2], bG1[2][2];

    // one tile: compute buf b, stage tile T2 -> buf b (regions recycled intra-buffer)
#define TILE(b, T2) do { \
    /* P0-pre: the tile's only exposed drain (12 reads) */ \
    READ_A(b); READ_BQ(b, 0, bG0); \
    asm volatile("s_waitcnt lgkmcnt(8)" ::: "memory"); \
    PH_MID(); \
    READ_BQ(b, 1, bG1);            /* serviced under q0 MFMA */ \
    MFMA_Q(0, bG0); \
    PH_END(); \
    /* P1-pre: A regions of buf b free (drained P0-MID, all waves by P0-END) */ \
    STAGE_A(b, 0, T2); STAGE_A(b, 1, T2); \
    PH_MID(); \
    READ_BQ(b, 2, bG0);            /* serviced under q1 MFMA */ \
    MFMA_Q(1, bG1); \
    PH_END(); \
    /* P2-pre: B3 (bG1 free after q1) -- small exposed drain */ \
    READ_BQ(b, 3, bG1); \
    PH_MID(); \
    MFMA_Q(2, bG0); \
    PH_END(); \
    /* P3-pre: all B reads of buf b drained by P2-MID + P2-END barrier */ \
    STAGE_B(b, 0, T2); STAGE_B(b, 1, T2); \
    PH_MID(); \
    MFMA_Q(3, bG1); \
    PH_END_VM8();                  /* oldest 8 = prev tile's stage -> next buf landed */ \
  } while (0)

    // ---- prologue: t0 -> buf0 (8), t1 -> buf1 (8); wait t0 landed ----
    STAGE_A(0, 0, 0); STAGE_A(0, 1, 0); STAGE_B(0, 0, 0); STAGE_B(0, 1, 0);
    STAGE_A(1, 0, 1); STAGE_A(1, 1, 1); STAGE_B(1, 0, 1); STAGE_B(1, 1, 1);
    asm volatile("s_waitcnt vmcnt(8)" ::: "memory");
    __builtin_amdgcn_s_barrier();
    __builtin_amdgcn_sched_barrier(0);

    for (int it = 0; it < NKT / 2; ++it) {
        TILE(0, (2 * it + 2) & (NKT - 1));   // wraps harmlessly on last iters
        TILE(1, (2 * it + 3) & (NKT - 1));
    }

    // ---- epilogue: out = round((is*ws[n]*acc + bias[n]) / os) ----
    const float is = p_is[0];
    const float inv_os = 1.0f / p_os[0];
    const int colBase = n0 + wni * 128;

    float alpha[8], beta[8];
#pragma unroll
    for (int nj = 0; nj < 8; ++nj) {
        const int col = colBase + nj * 16 + r16;
        alpha[nj] = is * wscale[col] * inv_os;
        beta[nj]  = (float)bias[col] * inv_os;
    }

    // C/D layout (verified m89/m91, dtype-independent): col = lane&15, row = quad*4 + reg
#pragma unroll
    for (int mi = 0; mi < 4; ++mi) {
        const int row0 = m0 + wmi * 64 + mi * 16 + quad * 4;
#pragma unroll
        for (int nj = 0; nj < 8; ++nj) {
            const int col = colBase + nj * 16 + r16;
#pragma unroll
            for (int reg = 0; reg < 4; ++reg) {
                const float v = acc[mi][nj][reg] * alpha[nj] + beta[nj];
                __builtin_nontemporal_store(__float2int_rn(v),
                                            out + (int64_t)(row0 + reg) * NDIM + col);
            }
        }
    }
}

extern "C" void kernel_launch(void* const* d_in, const int* in_sizes, int n_in,
                              void* d_out, int out_size, void* d_ws, size_t ws_size,
                              hipStream_t stream) {
    (void)in_sizes; (void)n_in; (void)out_size; (void)ws_size;
    const float* x      = (const float*)d_in[0];
    const int*   weight = (const int*)d_in[1];
    const int*   bias   = (const int*)d_in[2];
    const float* wscale = (const float*)d_in[3];
    const float* p_is   = (const float*)d_in[4];
    const float* p_os   = (const float*)d_in[5];

    // workspace: xq fp16 [M,K] (64 MiB) + wq fp16 [N,K] (32 MiB) = 96 MiB
    short* xq = (short*)d_ws;
    short* wq = xq + (size_t)MDIM * KDIM;

    quant_kernel<<<3072, 256, 0, stream>>>(x, xq, weight, wq, p_is);

    dim3 grid(NDIM / 256, MDIM / 256);   // 16 x 32 = 512 blocks
    gemm_f16_kernel<<<grid, 512, 0, stream>>>(xq, wq, bias, wscale, p_is, p_os, (int*)d_out);
}